// Round 1
// baseline (1161.010 us; speedup 1.0000x reference)
//
#include <hip/hip_runtime.h>

// LowRankINRLayer: out[b,n,o] = relu( sum_r ( sum_d x[b,n,d]*v[b,r,d] ) * W[o,r] )
// B=16, N=8192, DI=512, DO=512, R=32, all fp32.
// Memory-bound: 512 MB in+out @ ~6.3 TB/s => ~82 us floor. 8.6 GFLOP fp32 VALU (~55 us).
// Strategy: 1 thread per row n. xv[32] accumulators in VGPRs; v_mat and W are
// wave-uniform -> scalar loads (K$), no LDS, no shuffles.

#define B_  16
#define N_  8192
#define DI_ 512
#define DO_ 512
#define R_  32

__global__ __launch_bounds__(256, 2) void lowrank_fused(
    const float* __restrict__ x, const float* __restrict__ v,
    const float* __restrict__ W, float* __restrict__ out)
{
    const int bid = blockIdx.x;
    const int b = bid >> 5;                       // 32 blocks per batch (8192/256)
    const int n = ((bid & 31) << 8) | threadIdx.x;
    const size_t row = (size_t)b * N_ + n;
    const float* __restrict__ xrow = x + row * DI_;
    const float* __restrict__ vb   = v + (size_t)b * (R_ * DI_);

    float acc[R_];
#pragma unroll
    for (int r = 0; r < R_; ++r) acc[r] = 0.0f;

    // Phase 1: xv[r] = sum_d x[row][d] * v[b][r][d]
#pragma unroll 2
    for (int d = 0; d < DI_; d += 8) {
        const float4 x0 = *(const float4*)(xrow + d);
        const float4 x1 = *(const float4*)(xrow + d + 4);
#pragma unroll
        for (int r = 0; r < R_; ++r) {
            const float* vr = vb + r * DI_ + d;   // wave-uniform address -> s_load
            const float4 v0 = *(const float4*)(vr);
            const float4 v1 = *(const float4*)(vr + 4);
            acc[r] = fmaf(x0.x, v0.x, acc[r]);
            acc[r] = fmaf(x0.y, v0.y, acc[r]);
            acc[r] = fmaf(x0.z, v0.z, acc[r]);
            acc[r] = fmaf(x0.w, v0.w, acc[r]);
            acc[r] = fmaf(x1.x, v1.x, acc[r]);
            acc[r] = fmaf(x1.y, v1.y, acc[r]);
            acc[r] = fmaf(x1.z, v1.z, acc[r]);
            acc[r] = fmaf(x1.w, v1.w, acc[r]);
        }
    }

    // Phase 2: out[row][o] = relu( sum_r xv[r] * W[o][r] )
    float* __restrict__ orow = out + row * DO_;
#pragma unroll 2
    for (int o = 0; o < DO_; o += 4) {
        float s0 = 0.f, s1 = 0.f, s2 = 0.f, s3 = 0.f;
#pragma unroll
        for (int r = 0; r < R_; ++r) {
            const float a = acc[r];
            s0 = fmaf(a, W[(o + 0) * R_ + r], s0);   // W uniform -> s_load
            s1 = fmaf(a, W[(o + 1) * R_ + r], s1);
            s2 = fmaf(a, W[(o + 2) * R_ + r], s2);
            s3 = fmaf(a, W[(o + 3) * R_ + r], s3);
        }
        float4 res;
        res.x = fmaxf(s0, 0.f);
        res.y = fmaxf(s1, 0.f);
        res.z = fmaxf(s2, 0.f);
        res.w = fmaxf(s3, 0.f);
        *(float4*)(orow + o) = res;
    }
}

extern "C" void kernel_launch(void* const* d_in, const int* in_sizes, int n_in,
                              void* d_out, int out_size, void* d_ws, size_t ws_size,
                              hipStream_t stream) {
    const float* x  = (const float*)d_in[0];
    const float* v  = (const float*)d_in[1];
    const float* W  = (const float*)d_in[2];
    float* out      = (float*)d_out;

    const int threads = 256;
    const int blocks  = (B_ * N_) / threads;   // 512 blocks
    lowrank_fused<<<blocks, threads, 0, stream>>>(x, v, W, out);
}

// Round 2
// 1131.328 us; speedup vs baseline: 1.0262x; 1.0262x over previous
//
#include <hip/hip_runtime.h>

// LowRankINRLayer: out[b,n,o] = relu( sum_r ( sum_d x[b,n,d]*v[b,r,d] ) * W[o,r] )
// B=16, N=8192, DI=512, DO=512, R=32, all fp32.
// Memory floor: x 256MB + out 256MB + v/W 4.3MB @ ~6.3 TB/s => ~82 us.
// fp32 VALU compute: 8.6 GFLOP @ 157 TF => ~55 us. Memory-bound if coalesced.
//
// Round-1 failure: per-thread-row stores -> 2.55x HBM write amplification
// (WRITE_SIZE 653MB vs 256MB), grid of 512 blocks -> 24% occupancy, 863 us.
//
// This version:
//  Phase 1: 64 rows/block; thread (rl, p) = (t>>3, t&7) owns rows {rl, rl+32}
//    and d-slice {p*4 + 32k}. x loads coalesced (128B per 8-lane group).
//    32 rank-accumulators per row; 3-level shfl_xor butterfly over p; p==0
//    lanes write xv to LDS (row stride 36 floats: conflict-free, 16B aligned).
//  Phase 2: thread t holds W rows {2t, 2t+1} in VGPRs; loops 64 rows reading
//    xv via broadcast ds_read_b128; float2 stores -> 512B contiguous per wave.

#define B_  16
#define N_  8192
#define DI_ 512
#define DO_ 512
#define R_  32

#define ROWS   64     // rows per block
#define XV_LD  36     // padded LDS row stride (floats): banks spread, 16B aligned

__global__ __launch_bounds__(256, 4) void lowrank_fused(
    const float* __restrict__ x, const float* __restrict__ v,
    const float* __restrict__ W, float* __restrict__ out)
{
    __shared__ float xv_s[ROWS * XV_LD];   // 9216 B

    const int t  = threadIdx.x;
    const int p  = t & 7;                  // d-part 0..7
    const int rl = t >> 3;                 // row-local 0..31 (owns rl and rl+32)
    const int bidx = blockIdx.x;
    const int b = bidx >> 7;               // 128 blocks per batch (8192/64)
    const int row_base = (bidx & 127) << 6;

    const size_t rbase = (size_t)b * N_ + row_base;
    const float* __restrict__ xr0 = x + (rbase + rl) * DI_ + p * 4;
    const float* __restrict__ xr1 = xr0 + 32 * DI_;
    const float* __restrict__ vb  = v + (size_t)b * (R_ * DI_) + p * 4;

    float acc0[R_], acc1[R_];
#pragma unroll
    for (int r = 0; r < R_; ++r) { acc0[r] = 0.f; acc1[r] = 0.f; }

    // Phase 1: partial dots over this thread's 64 d-elements (16 float4 steps)
#pragma unroll 2
    for (int k = 0; k < 16; ++k) {
        const float4 xa = *(const float4*)(xr0 + 32 * k);
        const float4 xb = *(const float4*)(xr1 + 32 * k);
#pragma unroll
        for (int r = 0; r < R_; ++r) {
            const float4 vv = *(const float4*)(vb + r * DI_ + 32 * k);
            acc0[r] = fmaf(xa.x, vv.x, acc0[r]);
            acc0[r] = fmaf(xa.y, vv.y, acc0[r]);
            acc0[r] = fmaf(xa.z, vv.z, acc0[r]);
            acc0[r] = fmaf(xa.w, vv.w, acc0[r]);
            acc1[r] = fmaf(xb.x, vv.x, acc1[r]);
            acc1[r] = fmaf(xb.y, vv.y, acc1[r]);
            acc1[r] = fmaf(xb.z, vv.z, acc1[r]);
            acc1[r] = fmaf(xb.w, vv.w, acc1[r]);
        }
    }

    // Butterfly reduce across the 8 d-part lanes (xor 1,2,4)
#pragma unroll
    for (int r = 0; r < R_; ++r) {
        acc0[r] += __shfl_xor(acc0[r], 1, 64);
        acc1[r] += __shfl_xor(acc1[r], 1, 64);
    }
#pragma unroll
    for (int r = 0; r < R_; ++r) {
        acc0[r] += __shfl_xor(acc0[r], 2, 64);
        acc1[r] += __shfl_xor(acc1[r], 2, 64);
    }
#pragma unroll
    for (int r = 0; r < R_; ++r) {
        acc0[r] += __shfl_xor(acc0[r], 4, 64);
        acc1[r] += __shfl_xor(acc1[r], 4, 64);
    }

    if (p == 0) {
        float* d0 = &xv_s[rl * XV_LD];
        float* d1 = &xv_s[(rl + 32) * XV_LD];
#pragma unroll
        for (int j = 0; j < 8; ++j) {
            float4 a = make_float4(acc0[4*j], acc0[4*j+1], acc0[4*j+2], acc0[4*j+3]);
            float4 c = make_float4(acc1[4*j], acc1[4*j+1], acc1[4*j+2], acc1[4*j+3]);
            *(float4*)(d0 + 4*j) = a;
            *(float4*)(d1 + 4*j) = c;
        }
    }
    __syncthreads();

    // Phase 2: thread t -> output columns {2t, 2t+1} for all 64 rows.
    float4 W0[8], W1[8];
    {
        const float* Wp = W + (size_t)(2 * t) * R_;
#pragma unroll
        for (int j = 0; j < 8; ++j) {
            W0[j] = *(const float4*)(Wp + 4*j);
            W1[j] = *(const float4*)(Wp + R_ + 4*j);
        }
    }

    float* __restrict__ obase = out + rbase * DO_ + 2 * t;
#pragma unroll 2
    for (int row = 0; row < ROWS; ++row) {
        const float* xvr = &xv_s[row * XV_LD];
        float s0 = 0.f, s1 = 0.f;
#pragma unroll
        for (int j = 0; j < 8; ++j) {
            const float4 xf = *(const float4*)(xvr + 4*j);
            s0 = fmaf(xf.x, W0[j].x, s0);
            s0 = fmaf(xf.y, W0[j].y, s0);
            s0 = fmaf(xf.z, W0[j].z, s0);
            s0 = fmaf(xf.w, W0[j].w, s0);
            s1 = fmaf(xf.x, W1[j].x, s1);
            s1 = fmaf(xf.y, W1[j].y, s1);
            s1 = fmaf(xf.z, W1[j].z, s1);
            s1 = fmaf(xf.w, W1[j].w, s1);
        }
        float2 res;
        res.x = fmaxf(s0, 0.f);
        res.y = fmaxf(s1, 0.f);
        *(float2*)(obase + (size_t)row * DO_) = res;
    }
}

extern "C" void kernel_launch(void* const* d_in, const int* in_sizes, int n_in,
                              void* d_out, int out_size, void* d_ws, size_t ws_size,
                              hipStream_t stream) {
    const float* x  = (const float*)d_in[0];
    const float* v  = (const float*)d_in[1];
    const float* W  = (const float*)d_in[2];
    float* out      = (float*)d_out;

    const int threads = 256;
    const int blocks  = (B_ * N_) / ROWS;   // 2048 blocks
    lowrank_fused<<<blocks, threads, 0, stream>>>(x, v, W, out);
}